// Round 9
// baseline (214.660 us; speedup 1.0000x reference)
//
#include <hip/hip_runtime.h>
#include <math.h>
#include <stdint.h>

#define HC 4
#define HIDDEN 4096
#define DIM (HC * HIDDEN)          // 16384 floats per row
#define MIXN ((2 + HC) * HC)       // 24
#define RPB 16                     // rows per block
#define THREADS 512
#define NWAVE 8
#define CPW 6                      // fn columns per wave  (4 col-groups)
#define RPW 8                      // rows per wave        (2 row-groups)
#define CHUNK 256                  // floats per row per K-chunk (1 KB)
#define NCHUNK (DIM / CHUNK)       // 64
#define NBUF 3                     // hs ring buffers
#define NROWS (2 * 4096)           // B*S = 8192
#define HC_EPS 1e-5f
#define NORM_EPS 1e-6f

#define PRE_OFF 0
#define POST_OFF (NROWS * HC)            // 32768
#define COMB_OFF (2 * NROWS * HC)        // 65536

typedef float f32x4 __attribute__((ext_vector_type(4)));

__device__ __forceinline__ void g2lds16_nt(const float* g, float* l) {
    // per-lane global src; LDS dest = wave-uniform base + lane*16. aux=2 -> NT.
    __builtin_amdgcn_global_load_lds(
        (const __attribute__((address_space(1))) uint32_t*)g,
        (__attribute__((address_space(3))) uint32_t*)l, 16, 0, 2);
}

// No 2nd __launch_bounds__ arg (rounds 4/5: ",4" pinned VGPR=64 -> huge spills).
__global__ __launch_bounds__(THREADS) void hyperconn_kernel(
    const float* __restrict__ hs,    // [NROWS][DIM]
    const float* __restrict__ fn,    // [MIXN][DIM]
    const float* __restrict__ base,  // [MIXN]
    const float* __restrict__ scale, // [3]
    float* __restrict__ out)
{
    const int tid  = threadIdx.x;
    const int wave = tid >> 6;
    const int lane = tid & 63;
    const int row0 = blockIdx.x * RPB;
    const int rg   = wave >> 2;          // row-group 0..1  (rows 8*rg .. 8*rg+7)
    const int cg   = wave & 3;           // col-group 0..3  (cols 6*cg .. 6*cg+5)
    const int mg   = cg * CPW;

    __shared__ __align__(16) float lds[NBUF][RPB][CHUNK];   // 48 KB hs ring
    __shared__ float s_fin[RPB * 25];

    float acc[RPW][CPW];                 // acc[k][j] <-> phys row 8*rg + ((2*cg+k)&7)
    #pragma unroll
    for (int k = 0; k < RPW; ++k)
        #pragma unroll
        for (int j = 0; j < CPW; ++j) acc[k][j] = 0.0f;
    float ssq0 = 0.0f, ssq1 = 0.0f;      // phys rows 8*rg+2*cg, +1  (k=0,1)

    const f32x4* __restrict__ fn4 = reinterpret_cast<const f32x4*>(fn);

    // stage chunk t: wave w stages phys rows 2w, 2w+1 (1 KB = 1 instr each)
    auto stage = [&](int t, int buf) {
        #pragma unroll
        for (int rr = 0; rr < 2; ++rr) {
            const int r = 2 * wave + rr;
            g2lds16_nt(hs + (size_t)(row0 + r) * DIM + t * CHUNK + lane * 4,
                       &lds[buf][r][0]);
        }
    };
    // prefetch fn chunk t into registers (6 coalesced dwordx4, L2-resident)
    auto fnload = [&](int t, f32x4 (&f)[CPW]) {
        #pragma unroll
        for (int j = 0; j < CPW; ++j)
            f[j] = fn4[(size_t)(mg + j) * (DIM / 4) + t * (CHUNK / 4) + lane];
    };
    auto compute = [&](int buf, f32x4 (&f)[CPW]) {
        #pragma unroll
        for (int k = 0; k < RPW; ++k) {
            const int pr = 8 * rg + ((2 * cg + k) & 7);   // runtime LDS addr: fine
            const f32x4 x = *reinterpret_cast<const f32x4*>(&lds[buf][pr][lane * 4]);
            if (k == 0) {  // own ssq rows at compile-time k (row-permuted read order)
                ssq0 = fmaf(x.x, x.x, ssq0); ssq0 = fmaf(x.y, x.y, ssq0);
                ssq0 = fmaf(x.z, x.z, ssq0); ssq0 = fmaf(x.w, x.w, ssq0);
            }
            if (k == 1) {
                ssq1 = fmaf(x.x, x.x, ssq1); ssq1 = fmaf(x.y, x.y, ssq1);
                ssq1 = fmaf(x.z, x.z, ssq1); ssq1 = fmaf(x.w, x.w, ssq1);
            }
            #pragma unroll
            for (int j = 0; j < CPW; ++j) {
                acc[k][j] = fmaf(x.x, f[j].x, acc[k][j]);
                acc[k][j] = fmaf(x.y, f[j].y, acc[k][j]);
                acc[k][j] = fmaf(x.z, f[j].z, acc[k][j]);
                acc[k][j] = fmaf(x.w, f[j].w, acc[k][j]);
            }
        }
    };

    // Prologue. QUEUE ORDER IS THE POINT: fn first, stages after, so the
    // steady-state wait for fn(t) (vmcnt(2)) leaves stage(t+1) in flight.
    f32x4 fA[CPW], fB[CPW];
    fnload(0, fA);
    asm volatile("" ::: "memory");       // keep fn-before-stage issue order
    stage(0, 0); stage(1, 1);

    #pragma unroll 1
    for (int t = 0; t < NCHUNK; t += 2) {
        // ---- even half: consume fA, prefetch fB ----
        if (t < NCHUNK - 2) asm volatile("s_waitcnt vmcnt(2)" ::: "memory");
        else                asm volatile("s_waitcnt vmcnt(0)" ::: "memory");
        __builtin_amdgcn_s_barrier();
        asm volatile("" ::: "memory");
        if (t + 1 < NCHUNK) fnload(t + 1, fB);
        asm volatile("" ::: "memory");   // fn issued BEFORE next stage
        if (t + 2 < NCHUNK) stage(t + 2, (t + 2) % NBUF);
        compute(t % NBUF, fA);

        // ---- odd half: consume fB, prefetch fA ----
        const int u = t + 1;             // u < NCHUNK (NCHUNK even)
        if (u < NCHUNK - 2) asm volatile("s_waitcnt vmcnt(2)" ::: "memory");
        else                asm volatile("s_waitcnt vmcnt(0)" ::: "memory");
        __builtin_amdgcn_s_barrier();
        asm volatile("" ::: "memory");
        if (u + 1 < NCHUNK) fnload(u + 1, fA);
        asm volatile("" ::: "memory");
        if (u + 2 < NCHUNK) stage(u + 2, (u + 2) % NBUF);
        compute(u % NBUF, fB);
    }

    // 64-lane butterfly reduce: 48 dot partials + 2 ssq per wave
    #pragma unroll
    for (int k = 0; k < RPW; ++k)
        #pragma unroll
        for (int j = 0; j < CPW; ++j) {
            float v = acc[k][j];
            #pragma unroll
            for (int off = 32; off >= 1; off >>= 1) v += __shfl_xor(v, off, 64);
            acc[k][j] = v;
        }
    #pragma unroll
    for (int off = 32; off >= 1; off >>= 1) ssq0 += __shfl_xor(ssq0, off, 64);
    #pragma unroll
    for (int off = 32; off >= 1; off >>= 1) ssq1 += __shfl_xor(ssq1, off, 64);

    if (lane == 0) {
        #pragma unroll
        for (int k = 0; k < RPW; ++k) {
            const int pr = 8 * rg + ((2 * cg + k) & 7);
            #pragma unroll
            for (int j = 0; j < CPW; ++j) s_fin[pr * 25 + mg + j] = acc[k][j];
        }
        s_fin[(8 * rg + 2 * cg) * 25 + 24]     = ssq0;
        s_fin[(8 * rg + 2 * cg + 1) * 25 + 24] = ssq1;
    }
    __syncthreads();

    // epilogue: one thread per row
    if (tid < RPB) {
        const int row = row0 + tid;
        const float* v = &s_fin[tid * 25];
        const float rs = 1.0f / sqrtf(v[24] * (1.0f / (float)DIM) + NORM_EPS);
        const float s0 = scale[0], s1 = scale[1], s2 = scale[2];

        #pragma unroll
        for (int i = 0; i < HC; ++i) {
            const float z = v[i] * rs * s0 + base[i];
            out[PRE_OFF + row * HC + i] = 1.0f / (1.0f + expf(-z)) + HC_EPS;
        }
        #pragma unroll
        for (int i = 0; i < HC; ++i) {
            const float z = v[HC + i] * rs * s1 + base[HC + i];
            out[POST_OFF + row * HC + i] = 2.0f / (1.0f + expf(-z));
        }

        float c[HC][HC];
        #pragma unroll
        for (int i = 0; i < HC; ++i) {
            float l[HC];
            #pragma unroll
            for (int j = 0; j < HC; ++j)
                l[j] = v[2 * HC + i * HC + j] * rs * s2 + base[2 * HC + i * HC + j];
            const float mx = fmaxf(fmaxf(l[0], l[1]), fmaxf(l[2], l[3]));
            float e[HC];
            float sum = 0.0f;
            #pragma unroll
            for (int j = 0; j < HC; ++j) { e[j] = expf(l[j] - mx); sum += e[j]; }
            const float inv = 1.0f / sum;
            #pragma unroll
            for (int j = 0; j < HC; ++j) c[i][j] = e[j] * inv + HC_EPS;
        }
        #pragma unroll
        for (int j = 0; j < HC; ++j) {
            const float cs = c[0][j] + c[1][j] + c[2][j] + c[3][j] + HC_EPS;
            const float inv = 1.0f / cs;
            c[0][j] *= inv; c[1][j] *= inv; c[2][j] *= inv; c[3][j] *= inv;
        }
        #pragma unroll
        for (int it = 0; it < 4; ++it) {
            #pragma unroll
            for (int i = 0; i < HC; ++i) {
                const float rsum = c[i][0] + c[i][1] + c[i][2] + c[i][3] + HC_EPS;
                const float inv = 1.0f / rsum;
                c[i][0] *= inv; c[i][1] *= inv; c[i][2] *= inv; c[i][3] *= inv;
            }
            #pragma unroll
            for (int j = 0; j < HC; ++j) {
                const float cs = c[0][j] + c[1][j] + c[2][j] + c[3][j] + HC_EPS;
                const float inv = 1.0f / cs;
                c[0][j] *= inv; c[1][j] *= inv; c[2][j] *= inv; c[3][j] *= inv;
            }
        }
        #pragma unroll
        for (int i = 0; i < HC; ++i)
            #pragma unroll
            for (int j = 0; j < HC; ++j)
                out[COMB_OFF + row * (HC * HC) + i * HC + j] = c[i][j];
    }
}

extern "C" void kernel_launch(void* const* d_in, const int* in_sizes, int n_in,
                              void* d_out, int out_size, void* d_ws, size_t ws_size,
                              hipStream_t stream) {
    const float* hs    = (const float*)d_in[0];
    const float* fn    = (const float*)d_in[1];
    const float* base  = (const float*)d_in[2];
    const float* scale = (const float*)d_in[3];
    float* out = (float*)d_out;

    const int grid = NROWS / RPB;  // 512 blocks, 2/CU -> fully co-resident
    hyperconn_kernel<<<grid, THREADS, 0, stream>>>(hs, fn, base, scale, out);
}

// Round 10
// 175.853 us; speedup vs baseline: 1.2207x; 1.2207x over previous
//
#include <hip/hip_runtime.h>
#include <math.h>
#include <stdint.h>

#define HC 4
#define HIDDEN 4096
#define DIM (HC * HIDDEN)          // 16384 floats per row
#define MIXN ((2 + HC) * HC)       // 24
#define RPB 8                      // rows per block
#define THREADS 256
#define NWAVE 4
#define MPW (MIXN / NWAVE)         // 6 gate columns per wave
#define CHUNK 256                  // floats per row per K-chunk (1 KB)
#define NCHUNK (DIM / CHUNK)       // 64
#define NROWS (2 * 4096)           // B*S = 8192
#define HC_EPS 1e-5f
#define NORM_EPS 1e-6f

#define PRE_OFF 0
#define POST_OFF (NROWS * HC)            // 32768
#define COMB_OFF (2 * NROWS * HC)        // 65536

typedef float f32x4 __attribute__((ext_vector_type(4)));

__device__ __forceinline__ void g2lds16_nt(const float* g, float* l) {
    // per-lane global src; LDS dest = wave-uniform base + lane*16. aux=2 -> NT.
    __builtin_amdgcn_global_load_lds(
        (const __attribute__((address_space(1))) uint32_t*)g,
        (__attribute__((address_space(3))) uint32_t*)l, 16, 0, 2);
}

// No 2nd __launch_bounds__ arg (rounds 4/5: ",4" pinned VGPR=64 -> huge spills).
__global__ __launch_bounds__(THREADS) void hyperconn_kernel(
    const float* __restrict__ hs,    // [NROWS][DIM]
    const float* __restrict__ fn,    // [MIXN][DIM]
    const float* __restrict__ base,  // [MIXN]
    const float* __restrict__ scale, // [3]
    float* __restrict__ out)
{
    const int tid  = threadIdx.x;
    const int wave = tid >> 6;
    const int lane = tid & 63;
    const int row0 = blockIdx.x * RPB;
    const int mg   = wave * MPW;          // this wave's first gate column

    __shared__ __align__(16) float lds[2][RPB][CHUNK];   // 16 KB double buffer
    __shared__ float s_fin[RPB * 25];

    float acc[RPB][MPW];                  // acc[k] <-> phys row (2*wave + k) & 7
    #pragma unroll
    for (int k = 0; k < RPB; ++k)
        #pragma unroll
        for (int j = 0; j < MPW; ++j) acc[k][j] = 0.0f;
    float ssq0 = 0.0f, ssq1 = 0.0f;       // phys rows 2*wave, 2*wave+1 (k = 0, 1)

    const f32x4* __restrict__ fn4 = reinterpret_cast<const f32x4*>(fn);

    // stage chunk t into lds[buf]: wave w stages its own two rows (1 KB = 1 op each)
    auto stage = [&](int t, int buf) {
        #pragma unroll
        for (int rr = 0; rr < 2; ++rr) {
            const int r = 2 * wave + rr;
            g2lds16_nt(hs + (size_t)(row0 + r) * DIM + t * CHUNK + lane * 4,
                       &lds[buf][r][0]);
        }
    };

    stage(0, 0);

    #pragma unroll 1
    for (int t = 0; t < NCHUNK; ++t) {
        // vmcnt(0)+barrier: only stage(t) is in the queue here (fn loads of t-1
        // were drained by their FMA waits), and it was issued a full compute
        // phase ago -> near-zero drain. Guarantees lds[t&1] ready for all waves.
        __syncthreads();

        // QUEUE ORDER IS THE WHOLE OPTIMIZATION:
        //  (1) fn loads for chunk t FIRST,
        //  (2) then stage(t+1).
        // The compiler's automatic wait for f[*] (vmcnt(<=2)) then leaves the
        // YOUNGER stage ops in flight, so stage(t+1) streams from HBM while we
        // compute chunk t. With fn issued last (rounds 6-8), waiting for fn
        // popped stage(t+1) too -> delivery and compute fully serialized.
        f32x4 f[MPW];
        #pragma unroll
        for (int j = 0; j < MPW; ++j)
            f[j] = fn4[(size_t)(mg + j) * (DIM / 4) + t * (CHUNK / 4) + lane];
        asm volatile("" ::: "memory");     // pin fn-before-stage issue order
        if (t + 1 < NCHUNK) stage(t + 1, (t + 1) & 1);

        // ---- compute chunk t from lds[t&1] ----
        const int buf = t & 1;
        #pragma unroll
        for (int k = 0; k < RPB; ++k) {
            const int pr = (2 * wave + k) & 7;     // runtime LDS addr: fine
            const f32x4 x = *reinterpret_cast<const f32x4*>(&lds[buf][pr][lane * 4]);
            if (k == 0) {  // own ssq rows at compile-time k (row-permuted order)
                ssq0 = fmaf(x.x, x.x, ssq0); ssq0 = fmaf(x.y, x.y, ssq0);
                ssq0 = fmaf(x.z, x.z, ssq0); ssq0 = fmaf(x.w, x.w, ssq0);
            }
            if (k == 1) {
                ssq1 = fmaf(x.x, x.x, ssq1); ssq1 = fmaf(x.y, x.y, ssq1);
                ssq1 = fmaf(x.z, x.z, ssq1); ssq1 = fmaf(x.w, x.w, ssq1);
            }
            #pragma unroll
            for (int j = 0; j < MPW; ++j) {
                acc[k][j] = fmaf(x.x, f[j].x, acc[k][j]);
                acc[k][j] = fmaf(x.y, f[j].y, acc[k][j]);
                acc[k][j] = fmaf(x.z, f[j].z, acc[k][j]);
                acc[k][j] = fmaf(x.w, f[j].w, acc[k][j]);
            }
        }
    }

    // 64-lane butterfly reduce: 48 dot partials + 2 ssq per wave
    #pragma unroll
    for (int k = 0; k < RPB; ++k)
        #pragma unroll
        for (int j = 0; j < MPW; ++j) {
            float v = acc[k][j];
            #pragma unroll
            for (int off = 32; off >= 1; off >>= 1) v += __shfl_xor(v, off, 64);
            acc[k][j] = v;
        }
    #pragma unroll
    for (int off = 32; off >= 1; off >>= 1) ssq0 += __shfl_xor(ssq0, off, 64);
    #pragma unroll
    for (int off = 32; off >= 1; off >>= 1) ssq1 += __shfl_xor(ssq1, off, 64);

    if (lane == 0) {
        #pragma unroll
        for (int k = 0; k < RPB; ++k) {
            const int pr = (2 * wave + k) & 7;
            #pragma unroll
            for (int j = 0; j < MPW; ++j) s_fin[pr * 25 + mg + j] = acc[k][j];
        }
        s_fin[(2 * wave) * 25 + 24]     = ssq0;
        s_fin[(2 * wave + 1) * 25 + 24] = ssq1;
    }
    __syncthreads();

    // epilogue: one thread per row
    if (tid < RPB) {
        const int row = row0 + tid;
        const float* v = &s_fin[tid * 25];
        const float rs = 1.0f / sqrtf(v[24] * (1.0f / (float)DIM) + NORM_EPS);
        const float s0 = scale[0], s1 = scale[1], s2 = scale[2];

        #pragma unroll
        for (int i = 0; i < HC; ++i) {
            const float z = v[i] * rs * s0 + base[i];
            out[PRE_OFF + row * HC + i] = 1.0f / (1.0f + expf(-z)) + HC_EPS;
        }
        #pragma unroll
        for (int i = 0; i < HC; ++i) {
            const float z = v[HC + i] * rs * s1 + base[HC + i];
            out[POST_OFF + row * HC + i] = 2.0f / (1.0f + expf(-z));
        }

        float c[HC][HC];
        #pragma unroll
        for (int i = 0; i < HC; ++i) {
            float l[HC];
            #pragma unroll
            for (int j = 0; j < HC; ++j)
                l[j] = v[2 * HC + i * HC + j] * rs * s2 + base[2 * HC + i * HC + j];
            const float mx = fmaxf(fmaxf(l[0], l[1]), fmaxf(l[2], l[3]));
            float e[HC];
            float sum = 0.0f;
            #pragma unroll
            for (int j = 0; j < HC; ++j) { e[j] = expf(l[j] - mx); sum += e[j]; }
            const float inv = 1.0f / sum;
            #pragma unroll
            for (int j = 0; j < HC; ++j) c[i][j] = e[j] * inv + HC_EPS;
        }
        #pragma unroll
        for (int j = 0; j < HC; ++j) {
            const float cs = c[0][j] + c[1][j] + c[2][j] + c[3][j] + HC_EPS;
            const float inv = 1.0f / cs;
            c[0][j] *= inv; c[1][j] *= inv; c[2][j] *= inv; c[3][j] *= inv;
        }
        #pragma unroll
        for (int it = 0; it < 4; ++it) {
            #pragma unroll
            for (int i = 0; i < HC; ++i) {
                const float rsum = c[i][0] + c[i][1] + c[i][2] + c[i][3] + HC_EPS;
                const float inv = 1.0f / rsum;
                c[i][0] *= inv; c[i][1] *= inv; c[i][2] *= inv; c[i][3] *= inv;
            }
            #pragma unroll
            for (int j = 0; j < HC; ++j) {
                const float cs = c[0][j] + c[1][j] + c[2][j] + c[3][j] + HC_EPS;
                const float inv = 1.0f / cs;
                c[0][j] *= inv; c[1][j] *= inv; c[2][j] *= inv; c[3][j] *= inv;
            }
        }
        #pragma unroll
        for (int i = 0; i < HC; ++i)
            #pragma unroll
            for (int j = 0; j < HC; ++j)
                out[COMB_OFF + row * (HC * HC) + i * HC + j] = c[i][j];
    }
}

extern "C" void kernel_launch(void* const* d_in, const int* in_sizes, int n_in,
                              void* d_out, int out_size, void* d_ws, size_t ws_size,
                              hipStream_t stream) {
    const float* hs    = (const float*)d_in[0];
    const float* fn    = (const float*)d_in[1];
    const float* base  = (const float*)d_in[2];
    const float* scale = (const float*)d_in[3];
    float* out = (float*)d_out;

    const int grid = NROWS / RPB;  // 1024 blocks, 4/CU -> fully co-resident
    hyperconn_kernel<<<grid, THREADS, 0, stream>>>(hs, fn, base, scale, out);
}